// Round 6
// baseline (866.301 us; speedup 1.0000x reference)
//
#include <hip/hip_runtime.h>
#include <stdint.h>

#define L_DIM 2048
#define B_DIM 32
#define D_DIM 1024
#define N_DIM 3072   // 3*D
#define K_DIM 1024
#define BD    32768  // B*D

typedef __bf16 bf16x8 __attribute__((ext_vector_type(8)));
typedef unsigned short ushort8 __attribute__((ext_vector_type(8)));
typedef float f32x4 __attribute__((ext_vector_type(4)));

typedef const __attribute__((address_space(1))) unsigned int* gq_t;
typedef __attribute__((address_space(3))) unsigned int* lq_t;

static __device__ __forceinline__ unsigned short f2bf(float f) {
  unsigned u = __float_as_uint(f);
  u += 0x7FFFu + ((u >> 16) & 1u);   // RNE
  return (unsigned short)(u >> 16);
}

static __device__ __forceinline__ float bf2f(unsigned short s) {
  return __uint_as_float(((unsigned)s) << 16);
}

// ---------- convert x chunk (f32) -> bf16, 8 elems/thread ----------
__global__ void k_convx(const float* __restrict__ x, unsigned short* __restrict__ xb, int n8) {
  int i = blockIdx.x * blockDim.x + threadIdx.x;
  if (i >= n8) return;
  const float4* p = reinterpret_cast<const float4*>(x) + (size_t)i * 2;
  float4 a = p[0], b = p[1];
  ushort8 o;
  o[0] = f2bf(a.x); o[1] = f2bf(a.y); o[2] = f2bf(a.z); o[3] = f2bf(a.w);
  o[4] = f2bf(b.x); o[5] = f2bf(b.y); o[6] = f2bf(b.z); o[7] = f2bf(b.w);
  reinterpret_cast<ushort8*>(xb)[i] = o;
}

// ---------- W (K,N=3072 interleaved 3d+k) f32 -> WT (N'=k*D+d, K) bf16 ----------
__global__ __launch_bounds__(256) void k_wt(const float* __restrict__ w, unsigned short* __restrict__ wt) {
  __shared__ unsigned short tile[64][65];
  const int bid = blockIdx.x;
  const int kb = bid & 15;          // K/64 tile
  const int db = (bid >> 4) & 15;   // D/64 tile
  const int kp = bid >> 8;          // plane 0..2
  const int t = threadIdx.x;
  const int c = t & 63;
  const int q = t >> 6;             // 0..3
#pragma unroll
  for (int i = 0; i < 16; ++i) {
    int r = q * 16 + i;             // k within tile
    float v = w[(size_t)(kb * 64 + r) * N_DIM + 3 * (db * 64 + c) + kp];
    tile[r][c] = f2bf(v);
  }
  __syncthreads();
  const int k = t & 63;
#pragma unroll
  for (int i = 0; i < 16; ++i) {
    int n = q * 16 + i;             // d within tile
    wt[(size_t)(kp * D_DIM + db * 64 + n) * K_DIM + kb * 64 + k] = tile[k][n];
  }
}

// ---------- per-column bias, plane layout: col j = k*D+d ----------
__global__ void k_biascol(const float* __restrict__ bias, float* __restrict__ bc) {
  int j = blockIdx.x * blockDim.x + threadIdx.x;
  if (j >= N_DIM) return;
  int k = j >> 10;
  int d = j & 1023;
  float v = 0.f;
  if (k == 1) v = bias[d];
  else if (k == 2) v = bias[D_DIM + d];
  bc[j] = v;
}

// ---------- 256x256 8-phase bf16 MFMA GEMM (T1+T2+T3+T4+T5), bn-fast ----------
__global__ __launch_bounds__(512, 2) void k_gemm(
    const unsigned short* __restrict__ A,
    const unsigned short* __restrict__ BT,
    const float* __restrict__ bc,
    unsigned short* __restrict__ C,
    int Mtiles)
{
  __shared__ unsigned short smem[65536];

  // --- block swizzle (bijective, 8 XCDs); bn fast so same-XCD neighbors share A panel
  const int nwg = gridDim.x;
  const int q8 = nwg >> 3, r8 = nwg & 7;
  const int xcd = blockIdx.x & 7, li = blockIdx.x >> 3;
  const int wg = (xcd < r8 ? xcd * (q8 + 1) : r8 * (q8 + 1) + (xcd - r8) * q8) + li;
  const int NT = N_DIM / 256;   // 12
  const int bn = wg % NT;
  const int bm = wg / NT;

  const int t  = threadIdx.x;
  const int w  = t >> 6;
  const int l  = t & 63;
  const int wr = w >> 2, wc = w & 3;
  const int wrb = wr * 128, wcb = wc * 64;
  const int l15 = l & 15, lg = l >> 4, lx = l & 7;
  const int kgp0 = (lg ^ lx) * 8;          // elem offset of ksub=0 octet
  const int kgp1 = ((4 + lg) ^ lx) * 8;    // ksub=1
  const int sr0 = w * 8 + (l >> 3);        // staging row within half
  const int kgs = (lx ^ (l >> 3)) * 8;     // swizzled source k-octet

  const unsigned short* Abase = A  + (size_t)(bm * 256) * K_DIM;
  const unsigned short* Bbase = BT + (size_t)(bn * 256) * K_DIM;

  f32x4 acc[8][4];
#pragma unroll
  for (int i = 0; i < 8; ++i)
#pragma unroll
    for (int j = 0; j < 4; ++j) acc[i][j] = f32x4{0.f, 0.f, 0.f, 0.f};

#define STAGE(G, growbase, T, ldsBase)                                                  \
  { const unsigned short* s0_ = (G) + (((size_t)((growbase) + sr0)) << 10) + (T) * 64 + kgs; \
    __builtin_amdgcn_global_load_lds((gq_t)s0_, (lq_t)&smem[(ldsBase) + w * 512], 16, 0, 0); \
    const unsigned short* s1_ = s0_ + (64 << 10);                                       \
    __builtin_amdgcn_global_load_lds((gq_t)s1_, (lq_t)&smem[(ldsBase) + 4096 + w * 512], 16, 0, 0); }

#define SB0(T, b) STAGE(Bbase, 0,   (T), (b) * 32768 + 16384)
#define SB1(T, b) STAGE(Bbase, 128, (T), (b) * 32768 + 16384 + 8192)
#define SA0(T, b) STAGE(Abase, 0,   (T), (b) * 32768)
#define SA1(T, b) STAGE(Abase, 128, (T), (b) * 32768 + 8192)

#define LDF(idx) __builtin_bit_cast(bf16x8, *reinterpret_cast<const ushort8*>(&smem[(idx)]))

  // ---- prologue: tile0 fully + SB0(1); wait tile0, SB0(1) stays in flight
  SB0(0, 0); SB1(0, 0); SA0(0, 0); SA1(0, 0); SB0(1, 1);
  asm volatile("s_waitcnt vmcnt(2)" ::: "memory");
  __builtin_amdgcn_s_barrier();

#pragma unroll 2
  for (int t0 = 0; t0 < 16; ++t0) {
    const int cur = t0 & 1, nxt = cur ^ 1;
    const int cA = cur * 32768, cB = cA + 16384;
    bf16x8 bfr[4][2];
#pragma unroll
    for (int q = 0; q < 4; ++q) {
      bf16x8 af[2][2];
      if (q == 0) {
#pragma unroll
        for (int nf = 0; nf < 4; ++nf) {
          const int nr = (wcb + nf * 16 + l15) * 64;
          bfr[nf][0] = LDF(cB + nr + kgp0);
          bfr[nf][1] = LDF(cB + nr + kgp1);
        }
      }
#pragma unroll
      for (int mf = 0; mf < 2; ++mf) {
        const int ar = (wrb + (q * 2 + mf) * 16 + l15) * 64;
        af[mf][0] = LDF(cA + ar + kgp0);
        af[mf][1] = LDF(cA + ar + kgp1);
      }
      if (q == 0 && t0 < 15) SB1(t0 + 1, nxt);
      if (q == 1 && t0 < 15) SA0(t0 + 1, nxt);
      if (q == 2 && t0 < 15) SA1(t0 + 1, nxt);
      if (q == 3 && t0 < 14) SB0(t0 + 2, cur);

      __builtin_amdgcn_s_barrier();
      __builtin_amdgcn_s_setprio(1);
#pragma unroll
      for (int mf = 0; mf < 2; ++mf)
#pragma unroll
        for (int nf = 0; nf < 4; ++nf) {
          acc[q * 2 + mf][nf] = __builtin_amdgcn_mfma_f32_16x16x32_bf16(af[mf][0], bfr[nf][0], acc[q * 2 + mf][nf], 0, 0, 0);
          acc[q * 2 + mf][nf] = __builtin_amdgcn_mfma_f32_16x16x32_bf16(af[mf][1], bfr[nf][1], acc[q * 2 + mf][nf], 0, 0, 0);
        }
      __builtin_amdgcn_s_setprio(0);
      if (q == 3) {
        if (t0 < 14)       asm volatile("s_waitcnt vmcnt(2)" ::: "memory");
        else if (t0 == 14) asm volatile("s_waitcnt vmcnt(0)" ::: "memory");
      }
      __builtin_amdgcn_s_barrier();
      __builtin_amdgcn_sched_barrier(0);
    }
  }

  // ---- epilogue: bias add, f32->bf16, store
  const int r4 = lg * 4;
  float badd[4];
#pragma unroll
  for (int nf = 0; nf < 4; ++nf) badd[nf] = bc[bn * 256 + wcb + nf * 16 + l15];
#pragma unroll
  for (int fm = 0; fm < 8; ++fm) {
    const int row = bm * 256 + wrb + fm * 16 + r4;
#pragma unroll
    for (int nf = 0; nf < 4; ++nf) {
      const int col = bn * 256 + wcb + nf * 16 + l15;
      unsigned short* out = C + (size_t)row * N_DIM + col;
#pragma unroll
      for (int i = 0; i < 4; ++i)
        out[(size_t)i * N_DIM] = f2bf(acc[fm][nf][i] + badd[nf]);
    }
  }
#undef STAGE
#undef SB0
#undef SB1
#undef SA0
#undef SA1
#undef LDF
}

// ---------- SRU recurrence over a chunk of Lc steps ----------
__global__ void k_rec(const unsigned short* __restrict__ xb,  // chunk (Lc, BD) bf16
                      const unsigned short* __restrict__ u3,  // chunk (Lc*32, 3072) bf16 planes
                      const float* __restrict__ wcv,
                      const float* __restrict__ sxp,
                      float* __restrict__ c_state,            // (BD)
                      float* __restrict__ h,                  // chunk base (Lc, BD) f32
                      int Lc)
{
  int tid = blockIdx.x * blockDim.x + threadIdx.x;
  if (tid >= BD) return;
  const int d = tid & (D_DIM - 1);
  const int b = tid >> 10;
  const float fw = wcv[d];
  const float rw = wcv[D_DIM + d];
  const float sx = sxp[0];
  float c = c_state[tid];

  const unsigned short* up = u3 + (size_t)b * N_DIM + d;
  const unsigned short* xp = xb + tid;
  float*                hp = h + tid;

#pragma unroll 16
  for (int l = 0; l < Lc; ++l) {
    float u0 = bf2f(up[0]);
    float u1 = bf2f(up[1024]);
    float u2 = bf2f(up[2048]);
    float xv = bf2f(xp[0]) * sx;
    float f = 1.f / (1.f + __expf(-(u1 + c * fw)));
    float r = 1.f / (1.f + __expf(-(u2 + c * rw)));
    c = u0 + (c - u0) * f;
    hp[0] = xv + (c - xv) * r;
    up += (size_t)32 * N_DIM;
    xp += BD;
    hp += BD;
  }
  c_state[tid] = c;
}

__global__ void k_copyc(const float* __restrict__ c_state, float* __restrict__ out) {
  int i = blockIdx.x * blockDim.x + threadIdx.x;
  if (i < BD) out[i] = c_state[i];
}

extern "C" void kernel_launch(void* const* d_in, const int* in_sizes, int n_in,
                              void* d_out, int out_size, void* d_ws, size_t ws_size,
                              hipStream_t stream) {
  const float* x    = (const float*)d_in[0];
  const float* w    = (const float*)d_in[1];
  const float* wcv  = (const float*)d_in[2];
  const float* bias = (const float*)d_in[3];
  const float* sx   = (const float*)d_in[4];
  float* hout = (float*)d_out;
  float* cout = hout + (size_t)L_DIM * BD;

  const size_t wt_bytes = (size_t)N_DIM * K_DIM * 2;
  const size_t bc_off   = wt_bytes;
  const size_t c_off    = bc_off + (size_t)N_DIM * 4;
  const size_t xbf_off  = c_off + (size_t)BD * 4;
  int Lc = 8;
  for (int cand : {1024, 512, 256, 128, 64, 32, 16, 8}) {
    // xbf chunk: cand*BD*2 ; u3 chunk bf16: cand*BD*3*2
    size_t need = xbf_off + (size_t)cand * 65536 + (size_t)cand * 196608 + 1024;
    if (need <= ws_size) { Lc = cand; break; }
  }
  char* wsb = (char*)d_ws;
  unsigned short* wt_p  = (unsigned short*)wsb;
  float*          bc_p  = (float*)(wsb + bc_off);
  float*          c_p   = (float*)(wsb + c_off);
  unsigned short* xbf_p = (unsigned short*)(wsb + xbf_off);
  unsigned short* u3_p  = (unsigned short*)(wsb + xbf_off + (size_t)Lc * 65536);

  hipMemsetAsync(c_p, 0, (size_t)BD * 4, stream);
  k_wt<<<(K_DIM / 64) * (D_DIM / 64) * 3, 256, 0, stream>>>(w, wt_p);
  k_biascol<<<(N_DIM + 255) / 256, 256, 0, stream>>>(bias, bc_p);

  const int nchunks = L_DIM / Lc;
  const int Mtiles  = (Lc * B_DIM) / 256;
  for (int ci = 0; ci < nchunks; ++ci) {
    const size_t base = (size_t)ci * Lc * BD;
    k_convx<<<(Lc * BD / 8 + 255) / 256, 256, 0, stream>>>(x + base, xbf_p, Lc * BD / 8);
    k_gemm<<<Mtiles * (N_DIM / 256), 512, 0, stream>>>(xbf_p, wt_p, bc_p, u3_p, Mtiles);
    k_rec<<<BD / 64, 64, 0, stream>>>(xbf_p, u3_p, wcv, sx, c_p, hout + base, Lc);
  }
  k_copyc<<<BD / 256, 256, 0, stream>>>(c_p, cout);
}

// Round 7
// 816.678 us; speedup vs baseline: 1.0608x; 1.0608x over previous
//
#include <hip/hip_runtime.h>
#include <stdint.h>

#define L_DIM 2048
#define B_DIM 32
#define D_DIM 1024
#define N_DIM 3072   // 3*D
#define K_DIM 1024
#define BD    32768  // B*D

typedef __bf16 bf16x8 __attribute__((ext_vector_type(8)));
typedef unsigned short ushort8 __attribute__((ext_vector_type(8)));
typedef float f32x4 __attribute__((ext_vector_type(4)));

typedef const __attribute__((address_space(1))) unsigned int* gq_t;
typedef __attribute__((address_space(3))) unsigned int* lq_t;

static __device__ __forceinline__ unsigned short f2bf(float f) {
  unsigned u = __float_as_uint(f);
  u += 0x7FFFu + ((u >> 16) & 1u);   // RNE
  return (unsigned short)(u >> 16);
}

static __device__ __forceinline__ float bf2f(unsigned short s) {
  return __uint_as_float(((unsigned)s) << 16);
}

// ---------- convert ALL of x (f32) -> bf16, 8 elems/thread, one pass ----------
__global__ void k_convx(const float* __restrict__ x, unsigned short* __restrict__ xb, int n8) {
  int i = blockIdx.x * blockDim.x + threadIdx.x;
  if (i >= n8) return;
  const float4* p = reinterpret_cast<const float4*>(x) + (size_t)i * 2;
  float4 a = p[0], b = p[1];
  ushort8 o;
  o[0] = f2bf(a.x); o[1] = f2bf(a.y); o[2] = f2bf(a.z); o[3] = f2bf(a.w);
  o[4] = f2bf(b.x); o[5] = f2bf(b.y); o[6] = f2bf(b.z); o[7] = f2bf(b.w);
  reinterpret_cast<ushort8*>(xb)[i] = o;
}

// ---------- W (K,N=3072 interleaved 3d+k) f32 -> WT (N'=k*D+d, K) bf16 ----------
__global__ __launch_bounds__(256) void k_wt(const float* __restrict__ w, unsigned short* __restrict__ wt) {
  __shared__ unsigned short tile[64][65];
  const int bid = blockIdx.x;
  const int kb = bid & 15;          // K/64 tile
  const int db = (bid >> 4) & 15;   // D/64 tile
  const int kp = bid >> 8;          // plane 0..2
  const int t = threadIdx.x;
  const int c = t & 63;
  const int q = t >> 6;             // 0..3
#pragma unroll
  for (int i = 0; i < 16; ++i) {
    int r = q * 16 + i;             // k within tile
    float v = w[(size_t)(kb * 64 + r) * N_DIM + 3 * (db * 64 + c) + kp];
    tile[r][c] = f2bf(v);
  }
  __syncthreads();
  const int k = t & 63;
#pragma unroll
  for (int i = 0; i < 16; ++i) {
    int n = q * 16 + i;             // d within tile
    wt[(size_t)(kp * D_DIM + db * 64 + n) * K_DIM + kb * 64 + k] = tile[k][n];
  }
}

// ---------- per-column bias, plane layout: col j = k*D+d ----------
__global__ void k_biascol(const float* __restrict__ bias, float* __restrict__ bc) {
  int j = blockIdx.x * blockDim.x + threadIdx.x;
  if (j >= N_DIM) return;
  int k = j >> 10;
  int d = j & 1023;
  float v = 0.f;
  if (k == 1) v = bias[d];
  else if (k == 2) v = bias[D_DIM + d];
  bc[j] = v;
}

// ---------- 256x256 8-phase bf16 MFMA GEMM (T1+T2+T3+T4+T5), bn-fast ----------
__global__ __launch_bounds__(512, 1) void k_gemm(
    const unsigned short* __restrict__ A,
    const unsigned short* __restrict__ BT,
    const float* __restrict__ bc,
    unsigned short* __restrict__ C,
    int Mtiles)
{
  __shared__ unsigned short smem[65536];

  // --- block swizzle (bijective, 8 XCDs); bn fast so same-XCD neighbors share A panel
  const int nwg = gridDim.x;
  const int q8 = nwg >> 3, r8 = nwg & 7;
  const int xcd = blockIdx.x & 7, li = blockIdx.x >> 3;
  const int wg = (xcd < r8 ? xcd * (q8 + 1) : r8 * (q8 + 1) + (xcd - r8) * q8) + li;
  const int NT = N_DIM / 256;   // 12
  const int bn = wg % NT;
  const int bm = wg / NT;

  const int t  = threadIdx.x;
  const int w  = t >> 6;
  const int l  = t & 63;
  const int wr = w >> 2, wc = w & 3;
  const int wrb = wr * 128, wcb = wc * 64;
  const int l15 = l & 15, lg = l >> 4, lx = l & 7;
  const int kgp0 = (lg ^ lx) * 8;          // elem offset of ksub=0 octet
  const int kgp1 = ((4 + lg) ^ lx) * 8;    // ksub=1
  const int sr0 = w * 8 + (l >> 3);        // staging row within half
  const int kgs = (lx ^ (l >> 3)) * 8;     // swizzled source k-octet

  const unsigned short* Abase = A  + (size_t)(bm * 256) * K_DIM;
  const unsigned short* Bbase = BT + (size_t)(bn * 256) * K_DIM;

  f32x4 acc[8][4];
#pragma unroll
  for (int i = 0; i < 8; ++i)
#pragma unroll
    for (int j = 0; j < 4; ++j) acc[i][j] = f32x4{0.f, 0.f, 0.f, 0.f};

#define STAGE(G, growbase, T, ldsBase)                                                  \
  { const unsigned short* s0_ = (G) + (((size_t)((growbase) + sr0)) << 10) + (T) * 64 + kgs; \
    __builtin_amdgcn_global_load_lds((gq_t)s0_, (lq_t)&smem[(ldsBase) + w * 512], 16, 0, 0); \
    const unsigned short* s1_ = s0_ + (64 << 10);                                       \
    __builtin_amdgcn_global_load_lds((gq_t)s1_, (lq_t)&smem[(ldsBase) + 4096 + w * 512], 16, 0, 0); }

#define SB0(T, b) STAGE(Bbase, 0,   (T), (b) * 32768 + 16384)
#define SB1(T, b) STAGE(Bbase, 128, (T), (b) * 32768 + 16384 + 8192)
#define SA0(T, b) STAGE(Abase, 0,   (T), (b) * 32768)
#define SA1(T, b) STAGE(Abase, 128, (T), (b) * 32768 + 8192)

#define LDF(idx) __builtin_bit_cast(bf16x8, *reinterpret_cast<const ushort8*>(&smem[(idx)]))

  // ---- prologue: tile0 fully + SB0(1); wait tile0, SB0(1) stays in flight
  SB0(0, 0); SB1(0, 0); SA0(0, 0); SA1(0, 0); SB0(1, 1);
  asm volatile("s_waitcnt vmcnt(2)" ::: "memory");
  __builtin_amdgcn_s_barrier();

#pragma unroll 2
  for (int t0 = 0; t0 < 16; ++t0) {
    const int cur = t0 & 1, nxt = cur ^ 1;
    const int cA = cur * 32768, cB = cA + 16384;
    bf16x8 bfr[4][2];
#pragma unroll
    for (int q = 0; q < 4; ++q) {
      bf16x8 af[2][2];
      if (q == 0) {
#pragma unroll
        for (int nf = 0; nf < 4; ++nf) {
          const int nr = (wcb + nf * 16 + l15) * 64;
          bfr[nf][0] = LDF(cB + nr + kgp0);
          bfr[nf][1] = LDF(cB + nr + kgp1);
        }
      }
#pragma unroll
      for (int mf = 0; mf < 2; ++mf) {
        const int ar = (wrb + (q * 2 + mf) * 16 + l15) * 64;
        af[mf][0] = LDF(cA + ar + kgp0);
        af[mf][1] = LDF(cA + ar + kgp1);
      }
      if (q == 0 && t0 < 15) SB1(t0 + 1, nxt);
      if (q == 1 && t0 < 15) SA0(t0 + 1, nxt);
      if (q == 2 && t0 < 15) SA1(t0 + 1, nxt);
      if (q == 3 && t0 < 14) SB0(t0 + 2, cur);

      __builtin_amdgcn_s_barrier();
      __builtin_amdgcn_s_setprio(1);
#pragma unroll
      for (int mf = 0; mf < 2; ++mf)
#pragma unroll
        for (int nf = 0; nf < 4; ++nf) {
          acc[q * 2 + mf][nf] = __builtin_amdgcn_mfma_f32_16x16x32_bf16(af[mf][0], bfr[nf][0], acc[q * 2 + mf][nf], 0, 0, 0);
          acc[q * 2 + mf][nf] = __builtin_amdgcn_mfma_f32_16x16x32_bf16(af[mf][1], bfr[nf][1], acc[q * 2 + mf][nf], 0, 0, 0);
        }
      __builtin_amdgcn_s_setprio(0);
      if (q == 3) {
        if (t0 < 14)       asm volatile("s_waitcnt vmcnt(2)" ::: "memory");
        else if (t0 == 14) asm volatile("s_waitcnt vmcnt(0)" ::: "memory");
      }
      __builtin_amdgcn_s_barrier();
      __builtin_amdgcn_sched_barrier(0);
    }
  }

  // ---- epilogue: bias add, f32->bf16, store
  const int r4 = lg * 4;
  float badd[4];
#pragma unroll
  for (int nf = 0; nf < 4; ++nf) badd[nf] = bc[bn * 256 + wcb + nf * 16 + l15];
#pragma unroll
  for (int fm = 0; fm < 8; ++fm) {
    const int row = bm * 256 + wrb + fm * 16 + r4;
#pragma unroll
    for (int nf = 0; nf < 4; ++nf) {
      const int col = bn * 256 + wcb + nf * 16 + l15;
      unsigned short* out = C + (size_t)row * N_DIM + col;
#pragma unroll
      for (int i = 0; i < 4; ++i)
        out[(size_t)i * N_DIM] = f2bf(acc[fm][nf][i] + badd[nf]);
    }
  }
#undef STAGE
#undef SB0
#undef SB1
#undef SA0
#undef SA1
#undef LDF
}

// ---------- SRU recurrence over a chunk of Lc steps ----------
__global__ void k_rec(const unsigned short* __restrict__ xb,  // chunk (Lc, BD) bf16
                      const unsigned short* __restrict__ u3,  // chunk (Lc*32, 3072) bf16 planes
                      const float* __restrict__ wcv,
                      const float* __restrict__ sxp,
                      float* __restrict__ c_state,            // (BD)
                      float* __restrict__ h,                  // chunk base (Lc, BD) f32
                      int Lc)
{
  int tid = blockIdx.x * blockDim.x + threadIdx.x;
  if (tid >= BD) return;
  const int d = tid & (D_DIM - 1);
  const int b = tid >> 10;
  const float fw = wcv[d];
  const float rw = wcv[D_DIM + d];
  const float sx = sxp[0];
  float c = c_state[tid];

  const unsigned short* up = u3 + (size_t)b * N_DIM + d;
  const unsigned short* xp = xb + tid;
  float*                hp = h + tid;

#pragma unroll 8
  for (int l = 0; l < Lc; ++l) {
    float u0 = bf2f(up[0]);
    float u1 = bf2f(up[1024]);
    float u2 = bf2f(up[2048]);
    float xv = bf2f(xp[0]) * sx;
    float f = 1.f / (1.f + __expf(-(u1 + c * fw)));
    float r = 1.f / (1.f + __expf(-(u2 + c * rw)));
    c = u0 + (c - u0) * f;
    hp[0] = xv + (c - xv) * r;
    up += (size_t)32 * N_DIM;
    xp += BD;
    hp += BD;
  }
  c_state[tid] = c;
}

__global__ void k_copyc(const float* __restrict__ c_state, float* __restrict__ out) {
  int i = blockIdx.x * blockDim.x + threadIdx.x;
  if (i < BD) out[i] = c_state[i];
}

extern "C" void kernel_launch(void* const* d_in, const int* in_sizes, int n_in,
                              void* d_out, int out_size, void* d_ws, size_t ws_size,
                              hipStream_t stream) {
  const float* x    = (const float*)d_in[0];
  const float* w    = (const float*)d_in[1];
  const float* wcv  = (const float*)d_in[2];
  const float* bias = (const float*)d_in[3];
  const float* sx   = (const float*)d_in[4];
  float* hout = (float*)d_out;
  float* cout = hout + (size_t)L_DIM * BD;

  const size_t wt_bytes  = (size_t)N_DIM * K_DIM * 2;
  const size_t bc_off    = wt_bytes;
  const size_t c_off     = bc_off + (size_t)N_DIM * 4;
  const size_t xbf_off   = c_off + (size_t)BD * 4;
  const size_t xbf_bytes = (size_t)L_DIM * BD * 2;   // full-x bf16: 134 MB
  const size_t u3_off    = xbf_off + xbf_bytes;
  int Lc = 8;
  for (int cand : {512, 256, 128, 64, 32, 16, 8}) {
    size_t need = u3_off + (size_t)cand * 196608 + 1024;   // u3 chunk bf16
    if (need <= ws_size) { Lc = cand; break; }
  }
  char* wsb = (char*)d_ws;
  unsigned short* wt_p  = (unsigned short*)wsb;
  float*          bc_p  = (float*)(wsb + bc_off);
  float*          c_p   = (float*)(wsb + c_off);
  unsigned short* xbf_p = (unsigned short*)(wsb + xbf_off);
  unsigned short* u3_p  = (unsigned short*)(wsb + u3_off);

  hipMemsetAsync(c_p, 0, (size_t)BD * 4, stream);
  k_wt<<<(K_DIM / 64) * (D_DIM / 64) * 3, 256, 0, stream>>>(w, wt_p);
  k_biascol<<<(N_DIM + 255) / 256, 256, 0, stream>>>(bias, bc_p);
  k_convx<<<(L_DIM * BD / 8) / 256, 256, 0, stream>>>(x, xbf_p, L_DIM * BD / 8);

  const int nchunks = L_DIM / Lc;
  const int Mtiles  = (Lc * B_DIM) / 256;
  for (int ci = 0; ci < nchunks; ++ci) {
    const size_t base = (size_t)ci * Lc * BD;
    k_gemm<<<Mtiles * (N_DIM / 256), 512, 0, stream>>>(xbf_p + base, wt_p, bc_p, u3_p, Mtiles);
    k_rec<<<BD / 64, 64, 0, stream>>>(xbf_p + base, u3_p, wcv, sx, c_p, hout + base, Lc);
  }
  k_copyc<<<BD / 256, 256, 0, stream>>>(c_p, cout);
}